// Round 1
// baseline (1451.836 us; speedup 1.0000x reference)
//
#include <hip/hip_runtime.h>
#include <stdint.h>

// CRITICAL: the reference is XLA-CPU float32; XLA emits separate fmul/fadd
// (no FMA contraction). Disable contraction so our rounding matches.
#pragma clang fp contract(off)

#define NEGF (-1e30f)
#define NROW 512
#define NCOL 4096

// ---------------------------------------------------------------------------
// XLA-CPU float32 math replicas.
// exp/log: Cephes-style polynomials as generated by
//   xla/service/cpu/llvm_ir_runtime.cc (GenerateVF32Exp / GenerateVF32Log),
//   which mirror Eigen3 / sse_mathfun.
// log1p/expm1: xla/service/elemental_ir_emitter.cc (EmitLog1p / EmitExpm1).
// All our call sites have non-positive exp args and positive normal log args,
// so the special-case selects (NaN/inf/denormal) are value-identical and
// omitted where provably inactive.
// ---------------------------------------------------------------------------

__device__ __forceinline__ float xla_exp(float x) {
#pragma clang fp contract(off)
  const float exp_hi = 88.3762626647950f;
  const float exp_lo = -88.3762626647949f;
  const float LOG2EF = 1.44269504088896341f;
  const float C1 = 0.693359375f;
  const float C2 = -2.12194440e-4f;
  float xc = fminf(fmaxf(x, exp_lo), exp_hi);
  float fx = floorf(xc * LOG2EF + 0.5f);
  float tmp = fx * C1;
  float z = fx * C2;
  float xr = xc - tmp;
  xr = xr - z;
  float z2 = xr * xr;
  float y = 1.9875691500E-4f;
  y = y * xr + 1.3981999507E-3f;
  y = y * xr + 8.3334519073E-3f;
  y = y * xr + 4.1665795894E-2f;
  y = y * xr + 1.6666665459E-1f;
  y = y * xr + 5.0000001201E-1f;
  y = y * z2 + xr;
  y = y + 1.0f;
  int n = (int)fx;                       // fptosi (fx integral)
  float p2n = __int_as_float((n + 127) << 23);
  float res = y * p2n;
  return fmaxf(res, x);                  // vsl.Max(mul, original_input)
}

__device__ __forceinline__ float xla_log(float xin0) {
#pragma clang fp contract(off)
  float xin = fmaxf(xin0, __int_as_float(0x00800000));  // clamp to min normal
  int bits = __float_as_int(xin);
  int e_int = (bits >> 23) - 126;
  float m = __int_as_float((bits & 0x007fffff) | 0x3f000000);  // [0.5,1)
  float e = (float)e_int;
  const float SQRTHF = 0.707106781186547524f;
  float mlt1 = (m < SQRTHF) ? 1.0f : 0.0f;
  float tmp2 = (m < SQRTHF) ? m : 0.0f;
  float xm = m - 1.0f;
  e = e - mlt1;
  xm = xm + tmp2;
  float z = xm * xm;
  float y = 7.0376836292E-2f;
  y = y * xm + -1.1514610310E-1f;
  y = y * xm + 1.1676998740E-1f;
  y = y * xm + -1.2420140846E-1f;
  y = y * xm + 1.4249322787E-1f;
  y = y * xm + -1.6668057665E-1f;
  y = y * xm + 2.0000714765E-1f;
  y = y * xm + -2.4999993993E-1f;
  y = y * xm + 3.3333331174E-1f;
  y = y * xm;
  y = y * z;
  y = e * -2.12194440e-4f + y;    // y += e*q1
  y = y - 0.5f * z;               // y -= 0.5*z
  float out = xm + y;
  out = e * 0.693359375f + out;   // out += e*q2
  return out;
}

__device__ __forceinline__ float xla_log1p(float v) {
#pragma clang fp contract(off)
  float lg = xla_log(v + 1.0f);
  float sm = (-0.5f * v + 1.0f) * v;     // FMul(FAdd(FMul(-0.5,x),1),x)
  return (fabsf(v) < 1e-4f) ? sm : lg;
}

__device__ __forceinline__ float xla_expm1(float v) {
#pragma clang fp contract(off)
  float ex = xla_exp(v);
  float lgv = ex - 1.0f;
  float sm = v + (v * v) * 0.5f;         // FAdd(x, FMul(FMul(x,x),0.5))
  return (fabsf(v) < 1e-5f) ? sm : lgv;
}

__device__ __forceinline__ float xla_logaddexp(float a, float b) {
#pragma clang fp contract(off)
  float amax = fmaxf(a, b);
  float delta = a - b;
  float t = xla_exp(-fabsf(delta));
  return amax + xla_log1p(t);
}

// ---------------------------------------------------------------------------
// Kernel A: theta = -softplus(-s)+1e-7 (= logp), logq = log1mexp(theta),
// with the reference's permute: row r=b*4+e, col i=i_*64+j_.
// Writes packed float2 {lp, lq} to ws.
// ---------------------------------------------------------------------------
__global__ __launch_bounds__(256) void prep_kernel(
    const float* __restrict__ scores, float2* __restrict__ packed) {
#pragma clang fp contract(off)
  int t = blockIdx.x * 256 + threadIdx.x;    // t in [0, 512*4096)
  int r = t >> 12;
  int i = t & 4095;
  int b = r >> 2, e = r & 3;
  int i_ = i >> 6, j_ = i & 63;
  float s = scores[(((size_t)b * 64 + i_) * 64 + j_) * 4 + e];
  float ns = -s;
  float sp = xla_logaddexp(ns, 0.0f);        // jax.nn.softplus(-s)
  float theta = -sp + 1e-7f;
  // log1mexp(theta)
  float xm = fminf(theta, -1e-7f);
  float lq;
  if (xm < -0.6931472f) {
    lq = xla_log1p(-xla_exp(xm));
  } else {
    lq = xla_log(-xla_expm1(xm));
  }
  packed[t] = make_float2(theta, lq);
}

// ---------------------------------------------------------------------------
// Kernel B: per row (one wave): backward suffix DP over i=4095..0 with the
// 33-entry count state on lanes 0..32. Fused decision-mask generation:
// the reference's sampling num == DP intermediate x1, den == DP output new.
// Then the sequential budget walk (lane 0) and a parallel 0/1 write-out.
// ---------------------------------------------------------------------------
__global__ __launch_bounds__(64) void dp_kernel(
    const float2* __restrict__ packed, const float* __restrict__ unif,
    float* __restrict__ out) {
#pragma clang fp contract(off)
  const int r = blockIdx.x;
  const int lane = threadIdx.x;
  const float2* pr = packed + (size_t)r * NCOL;
  const float* ur = unif + (size_t)r * NCOL;

  __shared__ unsigned long long mask[NCOL];  // 32 KB: 33-bit decision masks
  __shared__ unsigned long long dec[64];     // packed walk decisions

  const int j = lane;                        // budget index; active j<=32
  const bool active = (j <= 32);
  float carry = (j == 0) ? 0.0f : NEGF;      // logS[4096] = [0, NEG, ...]

  // prefetch step 4095
  float2 plq = pr[NCOL - 1];
  float uu = ur[NCOL - 1];

#pragma unroll 1
  for (int i = NCOL - 1; i >= 0; --i) {
    float lp = plq.x, lq = plq.y, u = uu;
    int ip = (i > 0) ? (i - 1) : 0;          // prefetch next iteration
    plq = pr[ip];
    uu = ur[ip];

    float sh = __shfl_up(carry, 1);          // carry[j-1]
    if (j == 0) sh = NEGF;
    float x1 = lp + sh;                      // == reference's sampling `num`
    float x2 = lq + carry;
    float amax = fmaxf(x1, x2);
    float delta = x1 - x2;
    float t = xla_exp(-fabsf(delta));
    float l = xla_log1p(t);
    float newv = amax + l;                   // logS[i][j] == sampling `den`

    // decision bit for budget j at step i (off the DP critical chain)
    float dd = x1 - newv;
    dd = fminf(dd, 0.0f);
    float p1 = xla_exp(dd);
    bool bit = active && (j > 0) && (u < p1);
    unsigned long long m = __ballot(bit);
    if (lane == 0) mask[i] = m;

    carry = newv;
  }
  __syncthreads();

  // sequential budget walk: r_budget starts at K=32; bit 0 of each mask is 0,
  // which encodes the reference's (r > 0) gate.
  if (lane == 0) {
    int rb = 32;
    unsigned long long cur = 0ull;
    for (int i = 0; i < NCOL; ++i) {
      unsigned long long bit = (mask[i] >> rb) & 1ull;
      cur |= bit << (i & 63);
      rb -= (int)bit;
      if ((i & 63) == 63) { dec[i >> 6] = cur; cur = 0ull; }
    }
  }
  __syncthreads();

  // write out[b, i_, j_, e] = bit(i = i_*64 + j_); forward value of
  // hard + mu - stop_grad(mu) equals hard to within 2.4e-7 (<< 2e-2 thr).
  const int b = r >> 2, e = r & 3;
#pragma unroll 1
  for (int g = 0; g < 64; ++g) {
    float v = ((dec[g] >> lane) & 1ull) ? 1.0f : 0.0f;
    out[(((size_t)b * 64 + g) * 64 + lane) * 4 + e] = v;
  }
}

// ---------------------------------------------------------------------------
extern "C" void kernel_launch(void* const* d_in, const int* in_sizes, int n_in,
                              void* d_out, int out_size, void* d_ws,
                              size_t ws_size, hipStream_t stream) {
  (void)in_sizes; (void)n_in; (void)out_size; (void)ws_size;
  const float* scores = (const float*)d_in[0];  // (128,64,64,4) f32
  const float* unif = (const float*)d_in[1];    // (512,4096) f32
  float* out = (float*)d_out;                   // (128,64,64,4) f32
  float2* packed = (float2*)d_ws;               // 512*4096*8B = 16 MB

  prep_kernel<<<(NROW * NCOL) / 256, 256, 0, stream>>>(scores, packed);
  dp_kernel<<<NROW, 64, 0, stream>>>(packed, unif, out);
}

// Round 2
// 1267.152 us; speedup vs baseline: 1.1457x; 1.1457x over previous
//
#include <hip/hip_runtime.h>
#include <stdint.h>

// CRITICAL: the reference is XLA-CPU float32; XLA emits separate fmul/fadd
// (no FMA contraction). Disable contraction so our rounding matches.
#pragma clang fp contract(off)

#define NEGF (-1e30f)
#define NROW 512
#define NCOL 4096

// ---------------------------------------------------------------------------
// XLA-CPU float32 math replicas (bit-exact vs reference; verified absmax 0.0).
// ---------------------------------------------------------------------------

__device__ __forceinline__ float xla_exp(float x) {
#pragma clang fp contract(off)
  const float exp_hi = 88.3762626647950f;
  const float exp_lo = -88.3762626647949f;
  const float LOG2EF = 1.44269504088896341f;
  const float C1 = 0.693359375f;
  const float C2 = -2.12194440e-4f;
  float xc = fminf(fmaxf(x, exp_lo), exp_hi);
  float fx = floorf(xc * LOG2EF + 0.5f);
  float tmp = fx * C1;
  float z = fx * C2;
  float xr = xc - tmp;
  xr = xr - z;
  float z2 = xr * xr;
  float y = 1.9875691500E-4f;
  y = y * xr + 1.3981999507E-3f;
  y = y * xr + 8.3334519073E-3f;
  y = y * xr + 4.1665795894E-2f;
  y = y * xr + 1.6666665459E-1f;
  y = y * xr + 5.0000001201E-1f;
  y = y * z2 + xr;
  y = y + 1.0f;
  int n = (int)fx;
  float p2n = __int_as_float((n + 127) << 23);
  float res = y * p2n;
  return fmaxf(res, x);
}

// Specialization for x <= 0 (all dp-chain call sites): fminf(x, exp_hi) is
// value-identical to x there, so it is dropped. Everything else untouched.
__device__ __forceinline__ float xla_exp_np(float x) {
#pragma clang fp contract(off)
  const float exp_lo = -88.3762626647949f;
  const float LOG2EF = 1.44269504088896341f;
  const float C1 = 0.693359375f;
  const float C2 = -2.12194440e-4f;
  float xc = fmaxf(x, exp_lo);
  float fx = floorf(xc * LOG2EF + 0.5f);
  float tmp = fx * C1;
  float z = fx * C2;
  float xr = xc - tmp;
  xr = xr - z;
  float z2 = xr * xr;
  float y = 1.9875691500E-4f;
  y = y * xr + 1.3981999507E-3f;
  y = y * xr + 8.3334519073E-3f;
  y = y * xr + 4.1665795894E-2f;
  y = y * xr + 1.6666665459E-1f;
  y = y * xr + 5.0000001201E-1f;
  y = y * z2 + xr;
  y = y + 1.0f;
  int n = (int)fx;
  float p2n = __int_as_float((n + 127) << 23);
  float res = y * p2n;
  return fmaxf(res, x);
}

__device__ __forceinline__ float xla_log(float xin0) {
#pragma clang fp contract(off)
  float xin = fmaxf(xin0, __int_as_float(0x00800000));
  int bits = __float_as_int(xin);
  int e_int = (bits >> 23) - 126;
  float m = __int_as_float((bits & 0x007fffff) | 0x3f000000);
  float e = (float)e_int;
  const float SQRTHF = 0.707106781186547524f;
  float mlt1 = (m < SQRTHF) ? 1.0f : 0.0f;
  float tmp2 = (m < SQRTHF) ? m : 0.0f;
  float xm = m - 1.0f;
  e = e - mlt1;
  xm = xm + tmp2;
  float z = xm * xm;
  float y = 7.0376836292E-2f;
  y = y * xm + -1.1514610310E-1f;
  y = y * xm + 1.1676998740E-1f;
  y = y * xm + -1.2420140846E-1f;
  y = y * xm + 1.4249322787E-1f;
  y = y * xm + -1.6668057665E-1f;
  y = y * xm + 2.0000714765E-1f;
  y = y * xm + -2.4999993993E-1f;
  y = y * xm + 3.3333331174E-1f;
  y = y * xm;
  y = y * z;
  y = e * -2.12194440e-4f + y;
  y = y - 0.5f * z;
  float out = xm + y;
  out = e * 0.693359375f + out;
  return out;
}

// Specialization for xin >= 1 (dp chain: xin = t+1, t in [0,1]): min-normal
// clamp is value-identical there, so dropped.
__device__ __forceinline__ float xla_log_ge1(float xin) {
#pragma clang fp contract(off)
  int bits = __float_as_int(xin);
  int e_int = (bits >> 23) - 126;
  float m = __int_as_float((bits & 0x007fffff) | 0x3f000000);
  float e = (float)e_int;
  const float SQRTHF = 0.707106781186547524f;
  float mlt1 = (m < SQRTHF) ? 1.0f : 0.0f;
  float tmp2 = (m < SQRTHF) ? m : 0.0f;
  float xm = m - 1.0f;
  e = e - mlt1;
  xm = xm + tmp2;
  float z = xm * xm;
  float y = 7.0376836292E-2f;
  y = y * xm + -1.1514610310E-1f;
  y = y * xm + 1.1676998740E-1f;
  y = y * xm + -1.2420140846E-1f;
  y = y * xm + 1.4249322787E-1f;
  y = y * xm + -1.6668057665E-1f;
  y = y * xm + 2.0000714765E-1f;
  y = y * xm + -2.4999993993E-1f;
  y = y * xm + 3.3333331174E-1f;
  y = y * xm;
  y = y * z;
  y = e * -2.12194440e-4f + y;
  y = y - 0.5f * z;
  float out = xm + y;
  out = e * 0.693359375f + out;
  return out;
}

__device__ __forceinline__ float xla_log1p(float v) {
#pragma clang fp contract(off)
  float lg = xla_log(v + 1.0f);
  float sm = (-0.5f * v + 1.0f) * v;
  return (fabsf(v) < 1e-4f) ? sm : lg;
}

__device__ __forceinline__ float xla_log1p_unit(float v) {  // v in [0,1]
#pragma clang fp contract(off)
  float lg = xla_log_ge1(v + 1.0f);
  float sm = (-0.5f * v + 1.0f) * v;
  return (fabsf(v) < 1e-4f) ? sm : lg;
}

__device__ __forceinline__ float xla_expm1(float v) {
#pragma clang fp contract(off)
  float ex = xla_exp(v);
  float lgv = ex - 1.0f;
  float sm = v + (v * v) * 0.5f;
  return (fabsf(v) < 1e-5f) ? sm : lgv;
}

__device__ __forceinline__ float xla_logaddexp(float a, float b) {
#pragma clang fp contract(off)
  float amax = fmaxf(a, b);
  float delta = a - b;
  float t = xla_exp(-fabsf(delta));
  return amax + xla_log1p(t);
}

// Cross-lane shift-up-by-1 on the VALU: DPP row_shr:1 (16-lane rows) with
// readlane fixups at the row boundaries (lanes 16 and 32). Lane 0 gets NEGF
// via the DPP 'old' operand. No LDS unit involved.
__device__ __forceinline__ float shift_up1(float x, int lane) {
  int xi = __float_as_int(x);
  int sh = __builtin_amdgcn_update_dpp(__float_as_int(NEGF), xi,
                                       0x111 /*row_shr:1*/, 0xf, 0xf, false);
  int c15 = __builtin_amdgcn_readlane(xi, 15);
  int c31 = __builtin_amdgcn_readlane(xi, 31);
  float r = __int_as_float(sh);
  if (lane == 16) r = __int_as_float(c15);
  if (lane == 32) r = __int_as_float(c31);
  return r;
}

// ---------------------------------------------------------------------------
// Kernel A: theta = -softplus(-s)+1e-7 (= logp), logq = log1mexp(theta).
// Unchanged from the verified round-1 kernel.
// ---------------------------------------------------------------------------
__global__ __launch_bounds__(256) void prep_kernel(
    const float* __restrict__ scores, float2* __restrict__ packed) {
#pragma clang fp contract(off)
  int t = blockIdx.x * 256 + threadIdx.x;
  int r = t >> 12;
  int i = t & 4095;
  int b = r >> 2, e = r & 3;
  int i_ = i >> 6, j_ = i & 63;
  float s = scores[(((size_t)b * 64 + i_) * 64 + j_) * 4 + e];
  float ns = -s;
  float sp = xla_logaddexp(ns, 0.0f);
  float theta = -sp + 1e-7f;
  float xm = fminf(theta, -1e-7f);
  float lq;
  if (xm < -0.6931472f) {
    lq = xla_log1p(-xla_exp(xm));
  } else {
    lq = xla_log(-xla_expm1(xm));
  }
  packed[t] = make_float2(theta, lq);
}

// ---------------------------------------------------------------------------
// Kernel B: per-row backward suffix DP (one wave, 33 budget states on lanes
// 0..32), with the decision path software-pipelined one step behind the carry
// chain so it fills the chain's latency gaps.
// ---------------------------------------------------------------------------
__global__ __launch_bounds__(64) void dp_kernel(
    const float2* __restrict__ packed, const float* __restrict__ unif,
    float* __restrict__ out) {
#pragma clang fp contract(off)
  const int r = blockIdx.x;
  const int lane = threadIdx.x;
  const float2* pr = packed + (size_t)r * NCOL;
  const float* ur = unif + (size_t)r * NCOL;

  __shared__ unsigned long long mask[NCOL];  // 32 KB decision masks
  __shared__ unsigned long long dec[64];

  const int j = lane;
  const bool elig = (j >= 1 && j <= 32);
  float carry = (j == 0) ? 0.0f : NEGF;

  float pend_dd = 0.0f, pend_u = 0.0f;

  // rotating prefetch registers, depth 2
  float2 c0 = pr[NCOL - 1];
  float cu0 = ur[NCOL - 1];
  float2 c1 = pr[NCOL - 2];
  float cu1 = ur[NCOL - 2];

#define CHAIN(LP, LQ, UU)                      \
  do {                                         \
    float sh = shift_up1(carry, lane);         \
    float x1 = (LP) + sh;                      \
    float x2 = (LQ) + carry;                   \
    float amax = fmaxf(x1, x2);                \
    float delta = x1 - x2;                     \
    float t = xla_exp_np(-fabsf(delta));       \
    float l = xla_log1p_unit(t);               \
    float newv = amax + l;                     \
    pend_dd = x1 - newv;                       \
    pend_u = (UU);                             \
    carry = newv;                              \
  } while (0)

#define FIN(IDX)                               \
  do {                                         \
    float dd = fminf(pend_dd, 0.0f);           \
    float p1 = xla_exp_np(dd);                 \
    bool bit = elig && (pend_u < p1);          \
    unsigned long long m = __ballot(bit);      \
    if (lane == 0) mask[IDX] = m;              \
  } while (0)

  // peeled step i = NCOL-1
  {
    float lp = c0.x, lq = c0.y, u = cu0;
    c0 = c1; cu0 = cu1;
    c1 = pr[NCOL - 3]; cu1 = ur[NCOL - 3];
    CHAIN(lp, lq, u);
  }

  for (int i = NCOL - 2; i >= 0; --i) {
    float lp = c0.x, lq = c0.y, u = cu0;
    c0 = c1; cu0 = cu1;
    int ip = (i >= 2) ? (i - 2) : 0;
    c1 = pr[ip]; cu1 = ur[ip];

    FIN(i + 1);        // finalize previous step's decision (overlaps chain)
    CHAIN(lp, lq, u);
  }
  FIN(0);

#undef CHAIN
#undef FIN

  __syncthreads();

  // sequential budget walk (lane 0), LDS reads batched 8-wide
  if (lane == 0) {
    int rb = 32;
    for (int g = 0; g < 64; ++g) {
      unsigned long long cur = 0ull;
      for (int h = 0; h < 8; ++h) {
        unsigned long long mm[8];
#pragma unroll
        for (int q = 0; q < 8; ++q) mm[q] = mask[g * 64 + h * 8 + q];
#pragma unroll
        for (int q = 0; q < 8; ++q) {
          unsigned long long b = (mm[q] >> rb) & 1ull;
          cur |= b << (h * 8 + q);
          rb -= (int)b;
        }
      }
      dec[g] = cur;
    }
  }
  __syncthreads();

  const int b = r >> 2, e = r & 3;
#pragma unroll 1
  for (int g = 0; g < 64; ++g) {
    float v = ((dec[g] >> lane) & 1ull) ? 1.0f : 0.0f;
    out[(((size_t)b * 64 + g) * 64 + lane) * 4 + e] = v;
  }
}

// ---------------------------------------------------------------------------
extern "C" void kernel_launch(void* const* d_in, const int* in_sizes, int n_in,
                              void* d_out, int out_size, void* d_ws,
                              size_t ws_size, hipStream_t stream) {
  (void)in_sizes; (void)n_in; (void)out_size; (void)ws_size;
  const float* scores = (const float*)d_in[0];  // (128,64,64,4) f32
  const float* unif = (const float*)d_in[1];    // (512,4096) f32
  float* out = (float*)d_out;                   // (128,64,64,4) f32
  float2* packed = (float2*)d_ws;               // 16 MB

  prep_kernel<<<(NROW * NCOL) / 256, 256, 0, stream>>>(scores, packed);
  dp_kernel<<<NROW, 64, 0, stream>>>(packed, unif, out);
}

// Round 3
// 1262.891 us; speedup vs baseline: 1.1496x; 1.0034x over previous
//
#include <hip/hip_runtime.h>
#include <stdint.h>

// CRITICAL: the reference is XLA-CPU float32; XLA emits separate fmul/fadd
// (no FMA contraction). Disable contraction so our rounding matches.
#pragma clang fp contract(off)

#define NEGF (-1e30f)
#define NROW 512
#define NCOL 4096

// ---------------------------------------------------------------------------
// XLA-CPU float32 math replicas (bit-exact vs reference; verified absmax 0.0).
// ---------------------------------------------------------------------------

__device__ __forceinline__ float xla_exp(float x) {
#pragma clang fp contract(off)
  const float exp_hi = 88.3762626647950f;
  const float exp_lo = -88.3762626647949f;
  const float LOG2EF = 1.44269504088896341f;
  const float C1 = 0.693359375f;
  const float C2 = -2.12194440e-4f;
  float xc = fminf(fmaxf(x, exp_lo), exp_hi);
  float fx = floorf(xc * LOG2EF + 0.5f);
  float tmp = fx * C1;
  float z = fx * C2;
  float xr = xc - tmp;
  xr = xr - z;
  float z2 = xr * xr;
  float y = 1.9875691500E-4f;
  y = y * xr + 1.3981999507E-3f;
  y = y * xr + 8.3334519073E-3f;
  y = y * xr + 4.1665795894E-2f;
  y = y * xr + 1.6666665459E-1f;
  y = y * xr + 5.0000001201E-1f;
  y = y * z2 + xr;
  y = y + 1.0f;
  int n = (int)fx;
  float p2n = __int_as_float((n + 127) << 23);
  float res = y * p2n;
  return fmaxf(res, x);
}

// Specialization for x <= 0: fminf(x, exp_hi) dropped (value-identical there).
__device__ __forceinline__ float xla_exp_np(float x) {
#pragma clang fp contract(off)
  const float exp_lo = -88.3762626647949f;
  const float LOG2EF = 1.44269504088896341f;
  const float C1 = 0.693359375f;
  const float C2 = -2.12194440e-4f;
  float xc = fmaxf(x, exp_lo);
  float fx = floorf(xc * LOG2EF + 0.5f);
  float tmp = fx * C1;
  float z = fx * C2;
  float xr = xc - tmp;
  xr = xr - z;
  float z2 = xr * xr;
  float y = 1.9875691500E-4f;
  y = y * xr + 1.3981999507E-3f;
  y = y * xr + 8.3334519073E-3f;
  y = y * xr + 4.1665795894E-2f;
  y = y * xr + 1.6666665459E-1f;
  y = y * xr + 5.0000001201E-1f;
  y = y * z2 + xr;
  y = y + 1.0f;
  int n = (int)fx;
  float p2n = __int_as_float((n + 127) << 23);
  float res = y * p2n;
  return fmaxf(res, x);
}

__device__ __forceinline__ float xla_log(float xin0) {
#pragma clang fp contract(off)
  float xin = fmaxf(xin0, __int_as_float(0x00800000));
  int bits = __float_as_int(xin);
  int e_int = (bits >> 23) - 126;
  float m = __int_as_float((bits & 0x007fffff) | 0x3f000000);
  float e = (float)e_int;
  const float SQRTHF = 0.707106781186547524f;
  float mlt1 = (m < SQRTHF) ? 1.0f : 0.0f;
  float tmp2 = (m < SQRTHF) ? m : 0.0f;
  float xm = m - 1.0f;
  e = e - mlt1;
  xm = xm + tmp2;
  float z = xm * xm;
  float y = 7.0376836292E-2f;
  y = y * xm + -1.1514610310E-1f;
  y = y * xm + 1.1676998740E-1f;
  y = y * xm + -1.2420140846E-1f;
  y = y * xm + 1.4249322787E-1f;
  y = y * xm + -1.6668057665E-1f;
  y = y * xm + 2.0000714765E-1f;
  y = y * xm + -2.4999993993E-1f;
  y = y * xm + 3.3333331174E-1f;
  y = y * xm;
  y = y * z;
  y = e * -2.12194440e-4f + y;
  y = y - 0.5f * z;
  float out = xm + y;
  out = e * 0.693359375f + out;
  return out;
}

// Specialization for xin >= 1: min-normal clamp dropped (value-identical).
__device__ __forceinline__ float xla_log_ge1(float xin) {
#pragma clang fp contract(off)
  int bits = __float_as_int(xin);
  int e_int = (bits >> 23) - 126;
  float m = __int_as_float((bits & 0x007fffff) | 0x3f000000);
  float e = (float)e_int;
  const float SQRTHF = 0.707106781186547524f;
  float mlt1 = (m < SQRTHF) ? 1.0f : 0.0f;
  float tmp2 = (m < SQRTHF) ? m : 0.0f;
  float xm = m - 1.0f;
  e = e - mlt1;
  xm = xm + tmp2;
  float z = xm * xm;
  float y = 7.0376836292E-2f;
  y = y * xm + -1.1514610310E-1f;
  y = y * xm + 1.1676998740E-1f;
  y = y * xm + -1.2420140846E-1f;
  y = y * xm + 1.4249322787E-1f;
  y = y * xm + -1.6668057665E-1f;
  y = y * xm + 2.0000714765E-1f;
  y = y * xm + -2.4999993993E-1f;
  y = y * xm + 3.3333331174E-1f;
  y = y * xm;
  y = y * z;
  y = e * -2.12194440e-4f + y;
  y = y - 0.5f * z;
  float out = xm + y;
  out = e * 0.693359375f + out;
  return out;
}

__device__ __forceinline__ float xla_log1p(float v) {
#pragma clang fp contract(off)
  float lg = xla_log(v + 1.0f);
  float sm = (-0.5f * v + 1.0f) * v;
  return (fabsf(v) < 1e-4f) ? sm : lg;
}

__device__ __forceinline__ float xla_log1p_unit(float v) {  // v in [0,1]
#pragma clang fp contract(off)
  float lg = xla_log_ge1(v + 1.0f);
  float sm = (-0.5f * v + 1.0f) * v;
  return (fabsf(v) < 1e-4f) ? sm : lg;
}

__device__ __forceinline__ float xla_expm1(float v) {
#pragma clang fp contract(off)
  float ex = xla_exp(v);
  float lgv = ex - 1.0f;
  float sm = v + (v * v) * 0.5f;
  return (fabsf(v) < 1e-5f) ? sm : lgv;
}

__device__ __forceinline__ float xla_logaddexp(float a, float b) {
#pragma clang fp contract(off)
  float amax = fmaxf(a, b);
  float delta = a - b;
  float t = xla_exp(-fabsf(delta));
  return amax + xla_log1p(t);
}

// Cross-lane shift-up-by-1, pure VALU, no SGPR round-trip on the chain:
// row_shr:1 covers lanes within 16-rows (lanes 0/16/32/48 take old=NEGF);
// row_bcast15 (0x142: lane15->16..31, lane31->32..47) supplies lanes 16/32;
// one cndmask with the loop-invariant (lane==16||lane==32) mask selects.
__device__ __forceinline__ float shift_up1(float x, bool fix) {
  int xi = __float_as_int(x);
  int negi = __float_as_int(NEGF);
  int a = __builtin_amdgcn_update_dpp(negi, xi, 0x111, 0xf, 0xf, false);
  int b = __builtin_amdgcn_update_dpp(negi, xi, 0x142, 0xf, 0xf, false);
  return __int_as_float(fix ? b : a);
}

// ---------------------------------------------------------------------------
// Kernel A: theta = -softplus(-s)+1e-7 (= logp), logq = log1mexp(theta).
// Unchanged (verified bit-exact).
// ---------------------------------------------------------------------------
__global__ __launch_bounds__(256) void prep_kernel(
    const float* __restrict__ scores, float2* __restrict__ packed) {
#pragma clang fp contract(off)
  int t = blockIdx.x * 256 + threadIdx.x;
  int r = t >> 12;
  int i = t & 4095;
  int b = r >> 2, e = r & 3;
  int i_ = i >> 6, j_ = i & 63;
  float s = scores[(((size_t)b * 64 + i_) * 64 + j_) * 4 + e];
  float ns = -s;
  float sp = xla_logaddexp(ns, 0.0f);
  float theta = -sp + 1e-7f;
  float xm = fminf(theta, -1e-7f);
  float lq;
  if (xm < -0.6931472f) {
    lq = xla_log1p(-xla_exp(xm));
  } else {
    lq = xla_log(-xla_expm1(xm));
  }
  packed[t] = make_float2(theta, lq);
}

// ---------------------------------------------------------------------------
// Kernel B: per-row backward suffix DP. Inputs staged through LDS in 512-step
// double-buffered chunks (coalesced vector loads -> vmcnt; inner loop reads
// uniform-address ds_read -> in-order countable lgkmcnt). No SMEM in the hot
// loop. Decision path pipelined one step behind the carry chain.
// ---------------------------------------------------------------------------
__global__ __launch_bounds__(64) void dp_kernel(
    const float2* __restrict__ packed, const float* __restrict__ unif,
    float* __restrict__ out) {
#pragma clang fp contract(off)
  const int r = blockIdx.x;
  const int lane = threadIdx.x;
  const float2* pr = packed + (size_t)r * NCOL;
  const float* ur = unif + (size_t)r * NCOL;

  __shared__ __align__(16) float2 A[1024];   // 2 x 512-step chunk buffers
  __shared__ __align__(16) float U[1024];
  __shared__ uint32_t mask32[4100];          // [4096]=dummy for pipeline head
  __shared__ unsigned long long dec[64];

  const bool fix = (lane == 16) || (lane == 32);
  const bool elig = (lane >= 1 && lane <= 32);
  float carry = (lane == 0) ? 0.0f : NEGF;

  float pend_dd = 0.0f, pend_u = 2.0f;  // first FIN -> dummy slot 4096

  // stage chunk c (global i in [(7-c)<<9, ...+512)) into buffer half c&1
#define STAGE(C)                                                        \
  do {                                                                  \
    const int lo_ = (7 - (C)) << 9;                                     \
    const int h_ = ((C) & 1) << 9;                                      \
    float4 a0 = *(const float4*)&pr[lo_ + 0 * 128 + 2 * lane];          \
    float4 a1 = *(const float4*)&pr[lo_ + 1 * 128 + 2 * lane];          \
    float4 a2 = *(const float4*)&pr[lo_ + 2 * 128 + 2 * lane];          \
    float4 a3 = *(const float4*)&pr[lo_ + 3 * 128 + 2 * lane];          \
    float4 u0 = *(const float4*)&ur[lo_ + 0 * 256 + 4 * lane];          \
    float4 u1 = *(const float4*)&ur[lo_ + 1 * 256 + 4 * lane];          \
    *(float4*)&A[h_ + 0 * 128 + 2 * lane] = a0;                         \
    *(float4*)&A[h_ + 1 * 128 + 2 * lane] = a1;                         \
    *(float4*)&A[h_ + 2 * 128 + 2 * lane] = a2;                         \
    *(float4*)&A[h_ + 3 * 128 + 2 * lane] = a3;                         \
    *(float4*)&U[h_ + 0 * 256 + 4 * lane] = u0;                         \
    *(float4*)&U[h_ + 1 * 256 + 4 * lane] = u1;                         \
  } while (0)

#define CHAIN(LP, LQ, UU)                      \
  do {                                         \
    float sh = shift_up1(carry, fix);          \
    float x1 = (LP) + sh;                      \
    float x2 = (LQ) + carry;                   \
    float amax = fmaxf(x1, x2);                \
    float delta = x1 - x2;                     \
    float t = xla_exp_np(-fabsf(delta));       \
    float l = xla_log1p_unit(t);               \
    float newv = amax + l;                     \
    pend_dd = x1 - newv;                       \
    pend_u = (UU);                             \
    carry = newv;                              \
  } while (0)

#define FIN(IDX)                                        \
  do {                                                  \
    float dd = fminf(pend_dd, 0.0f);                    \
    float p1 = xla_exp_np(dd);                          \
    bool bit = elig && (pend_u < p1);                   \
    unsigned long long m = __ballot(bit);               \
    if (lane == 0) mask32[IDX] = (uint32_t)(m >> 1);    \
  } while (0)

  STAGE(0);
  // prime rotation: steps n=4095 (flat idx 511), n=4094 (flat idx 510)
  float2 c0 = A[511];
  float cu0 = U[511];
  float2 c1 = A[510];
  float cu1 = U[510];

#pragma unroll 1
  for (int c = 0; c < 8; ++c) {
    if (c + 1 < 8) STAGE(c + 1);  // fills half (c+1)&1 before inner loop
#pragma unroll 1
    for (int t = 511; t >= 0; --t) {
      const int n = ((7 - c) << 9) + t;
      float lp = c0.x, lq = c0.y, u = cu0;
      c0 = c1;
      cu0 = cu1;
      int pn = (n >= 2) ? (n - 2) : 0;  // prefetch step n-2
      int fi = (((7 - (pn >> 9)) & 1) << 9) | (pn & 511);
      c1 = A[fi];
      cu1 = U[fi];

      FIN(n + 1);  // finalize previous step (overlaps chain latency)
      CHAIN(lp, lq, u);
    }
  }
  FIN(0);

#undef STAGE
#undef CHAIN
#undef FIN

  __syncthreads();

  // sequential budget walk (lane 0); masks store bits j=1..32 at bit j-1
  if (lane == 0) {
    int rb = 32;
    for (int g = 0; g < 64; ++g) {
      unsigned long long cur = 0ull;
      for (int h = 0; h < 8; ++h) {
        uint32_t mm[8];
#pragma unroll
        for (int q = 0; q < 8; ++q) mm[q] = mask32[g * 64 + h * 8 + q];
#pragma unroll
        for (int q = 0; q < 8; ++q) {
          unsigned b = (rb != 0) ? ((mm[q] >> (rb - 1)) & 1u) : 0u;
          cur |= (unsigned long long)b << (h * 8 + q);
          rb -= (int)b;
        }
      }
      dec[g] = cur;
    }
  }
  __syncthreads();

  const int b = r >> 2, e = r & 3;
#pragma unroll 1
  for (int g = 0; g < 64; ++g) {
    float v = ((dec[g] >> lane) & 1ull) ? 1.0f : 0.0f;
    out[(((size_t)b * 64 + g) * 64 + lane) * 4 + e] = v;
  }
}

// ---------------------------------------------------------------------------
extern "C" void kernel_launch(void* const* d_in, const int* in_sizes, int n_in,
                              void* d_out, int out_size, void* d_ws,
                              size_t ws_size, hipStream_t stream) {
  (void)in_sizes; (void)n_in; (void)out_size; (void)ws_size;
  const float* scores = (const float*)d_in[0];  // (128,64,64,4) f32
  const float* unif = (const float*)d_in[1];    // (512,4096) f32
  float* out = (float*)d_out;                   // (128,64,64,4) f32
  float2* packed = (float2*)d_ws;               // 16 MB

  prep_kernel<<<(NROW * NCOL) / 256, 256, 0, stream>>>(scores, packed);
  dp_kernel<<<NROW, 64, 0, stream>>>(packed, unif, out);
}